// Round 7
// baseline (755.996 us; speedup 1.0000x reference)
//
#include <hip/hip_runtime.h>

#define N_GRID 128
#define N_GRID3 (N_GRID * N_GRID * N_GRID)   // 2097152 cells/nodes

constexpr int   N_PART   = 500000;
constexpr float DT       = 0.0002f;
constexpr float DX       = 1.0f / 128.0f;
constexpr float INV_DX   = 128.0f;
constexpr float P_MASS   = 5.9604644775390625e-05f;   // (DX*0.5)^3 * 1000
constexpr float AFF_COEF = -7.8125e-07f;              // -DT * P_VOL * 4 * INV_DX^2
constexpr float GRAVITY  = 9.8f;
constexpr int   BOUND    = 3;
constexpr float C_SCALE  = 65536.0f;                  // 4 * INV_DX^2
constexpr int   ZQ       = 2;                         // z-nodes per p2g thread

// ---------------- pass 1: cell id histogram + particle-cell bbox ----------------
__global__ __launch_bounds__(256) void k_count(const float* __restrict__ x,
                                               int* __restrict__ cnt,
                                               int* __restrict__ bmin,
                                               int* __restrict__ bmax) {
  int n = blockIdx.x * 256 + threadIdx.x;
  bool valid = (n < N_PART);
  int bx = 0x7F7F7F7F, by = 0x7F7F7F7F, bz = 0x7F7F7F7F;
  int mx = 0, my = 0, mz = 0;
  if (valid) {
    bx = (int)floorf(x[n * 3 + 0] * INV_DX - 0.5f);
    by = (int)floorf(x[n * 3 + 1] * INV_DX - 0.5f);
    bz = (int)floorf(x[n * 3 + 2] * INV_DX - 0.5f);
    bx = min(max(bx, 0), N_GRID - 1);
    by = min(max(by, 0), N_GRID - 1);
    bz = min(max(bz, 0), N_GRID - 1);
    int c = (bx << 14) | (by << 7) | bz;
    atomicAdd(&cnt[c], 1);
    mx = bx; my = by; mz = bz;
  }
  // wave min/max reduce (64 lanes)
#pragma unroll
  for (int d = 32; d > 0; d >>= 1) {
    bx = min(bx, __shfl_xor(bx, d));
    by = min(by, __shfl_xor(by, d));
    bz = min(bz, __shfl_xor(bz, d));
    mx = max(mx, __shfl_xor(mx, d));
    my = max(my, __shfl_xor(my, d));
    mz = max(mz, __shfl_xor(mz, d));
  }
  if ((threadIdx.x & 63) == 0) {
    atomicMin(&bmin[0], bx);
    atomicMin(&bmin[1], by);
    atomicMin(&bmin[2], bz);
    atomicMax(&bmax[0], mx);
    atomicMax(&bmax[1], my);
    atomicMax(&bmax[2], mz);
  }
}

// ---------------- pass 2a: block sums (2048 blocks x 1024 bins) ----------------
__global__ __launch_bounds__(256) void k_scan1(const int* __restrict__ cnt,
                                               int* __restrict__ blkSum) {
  __shared__ int ws[4];
  int tid = threadIdx.x, lane = tid & 63, wid = tid >> 6;
  int4 v = ((const int4*)cnt)[blockIdx.x * 256 + tid];
  int s = v.x + v.y + v.z + v.w;
  for (int d = 32; d > 0; d >>= 1) s += __shfl_down(s, d);
  if (lane == 0) ws[wid] = s;
  __syncthreads();
  if (tid == 0) blkSum[blockIdx.x] = ws[0] + ws[1] + ws[2] + ws[3];
}

// ---------------- pass 2b: scan 2048 block sums (1 workgroup) ----------------
__global__ __launch_bounds__(256) void k_scan2(const int* __restrict__ blkSum,
                                               int* __restrict__ blkOff,
                                               int* __restrict__ start) {
  __shared__ int wsum[4];
  int tid = threadIdx.x, lane = tid & 63, wid = tid >> 6;
  int base = tid * 8;
  int s[8], tot = 0;
#pragma unroll
  for (int j = 0; j < 8; ++j) { s[j] = blkSum[base + j]; tot += s[j]; }
  int incl = tot;
  for (int d = 1; d < 64; d <<= 1) {
    int t = __shfl_up(incl, d);
    if (lane >= d) incl += t;
  }
  if (lane == 63) wsum[wid] = incl;
  __syncthreads();
  int woff = 0;
  for (int w = 0; w < wid; ++w) woff += wsum[w];
  int run = woff + incl - tot;
#pragma unroll
  for (int j = 0; j < 8; ++j) { blkOff[base + j] = run; run += s[j]; }
  if (tid == 255) start[N_GRID3] = run;  // == N_PART
}

// ------- pass 2c: in-block exclusive scan + offset; cursor written over cnt -------
__global__ __launch_bounds__(256) void k_scan3(int* __restrict__ cnt,
                                               const int* __restrict__ blkOff,
                                               int* __restrict__ start) {
  __shared__ int wsum[4];
  int tid = threadIdx.x, lane = tid & 63, wid = tid >> 6;
  int b = blockIdx.x;
  int4 v = ((const int4*)cnt)[b * 256 + tid];
  int s = v.x + v.y + v.z + v.w;
  int incl = s;
  for (int d = 1; d < 64; d <<= 1) {
    int t = __shfl_up(incl, d);
    if (lane >= d) incl += t;
  }
  if (lane == 63) wsum[wid] = incl;
  __syncthreads();
  int woff = blkOff[b];
  for (int w = 0; w < wid; ++w) woff += wsum[w];
  int run = woff + incl - s;
  int i0 = (b * 256 + tid) * 4;
  int r0 = run, r1 = r0 + v.x, r2 = r1 + v.y, r3 = r2 + v.z;
  start[i0 + 0] = r0; start[i0 + 1] = r1; start[i0 + 2] = r2; start[i0 + 3] = r3;
  cnt[i0 + 0] = r0; cnt[i0 + 1] = r1; cnt[i0 + 2] = r2; cnt[i0 + 3] = r3;  // cursor
}

// ---------------- pass 3: reorder + precompute 64B particle payload ----------------
// payload[pos] = { (px,py,pz,mvx), (mvy,mvz,a0,a1), (a2,a3,a4,a5), (a6,a7,a8,pad) }
__global__ __launch_bounds__(256) void k_reorder(
    const float* __restrict__ x, const float* __restrict__ v,
    const float* __restrict__ C, const float* __restrict__ S,
    int* __restrict__ cursor, float4* __restrict__ pay) {
  int n = blockIdx.x * 256 + threadIdx.x;
  if (n >= N_PART) return;

  float px = x[n * 3 + 0], py = x[n * 3 + 1], pz = x[n * 3 + 2];
  int bx = min(max((int)floorf(px * INV_DX - 0.5f), 0), N_GRID - 1);
  int by = min(max((int)floorf(py * INV_DX - 0.5f), 0), N_GRID - 1);
  int bz = min(max((int)floorf(pz * INV_DX - 0.5f), 0), N_GRID - 1);
  int c = (bx << 14) | (by << 7) | bz;
  int pos = atomicAdd(&cursor[c], 1);

  float mvx = P_MASS * v[n * 3 + 0];
  float mvy = P_MASS * v[n * 3 + 1];
  float mvz = P_MASS * v[n * 3 + 2];
  float aff[9];
#pragma unroll
  for (int k = 0; k < 9; ++k)
    aff[k] = AFF_COEF * S[n * 9 + k] + P_MASS * C[n * 9 + k];

  float4* dst = pay + (size_t)pos * 4;
  dst[0] = make_float4(px, py, pz, mvx);
  dst[1] = make_float4(mvy, mvz, aff[0], aff[1]);
  dst[2] = make_float4(aff[2], aff[3], aff[4], aff[5]);
  dst[3] = make_float4(aff[6], aff[7], aff[8], 0.0f);
}

// quadratic B-spline weight for static offset o (folds after unroll)
__device__ __forceinline__ float wq(int o, float f) {
  if (o == 0) return 0.5f * (1.5f - f) * (1.5f - f);
  if (o == 1) return 0.75f - (f - 1.0f) * (f - 1.0f);
  return 0.5f * (f - 0.5f) * (f - 0.5f);
}

// ---------------- P2G gather: dense bbox launch, 2 z-nodes per thread ----------------
// Threads indexed densely inside the dilated particle bbox -> every resident wave
// is active and uniformly loaded. Zero atomics, zero LDS, register accumulation,
// fused normalize/gravity/boundary epilogue.
__global__ __launch_bounds__(256) void mpm_p2g(
    const int* __restrict__ start, const float4* __restrict__ pay,
    const int* __restrict__ bmin, const int* __restrict__ bmax,
    float* __restrict__ grid /* [N_GRID3][4] final velocities */) {
  int bx0 = bmin[0], by0 = bmin[1], bz0c = bmin[2];
  int nxd = bmax[0] - bx0 + 3;   // nodes touched per axis = cells + 2
  int nyd = bmax[1] - by0 + 3;
  int nzd = bmax[2] - bz0c + 3;
  int dimzq = (nzd + ZQ - 1) / ZQ;
  int vol = nxd * nyd * dimzq;

  int t = blockIdx.x * 256 + threadIdx.x;
  if (t >= vol) return;
  int izq = t % dimzq;
  int r = t / dimzq;
  int iy = r % nyd;
  int ix = r / nyd;
  int nx = bx0 + ix, ny = by0 + iy, nz0 = bz0c + izq * ZQ;
  if (nx > N_GRID - 1 || ny > N_GRID - 1) return;
  int zb0 = nz0 - 2;  // first contributing cell

  float accx[ZQ], accy[ZQ], accz[ZQ], accm[ZQ];
#pragma unroll
  for (int k = 0; k < ZQ; ++k) { accx[k] = 0.f; accy[k] = 0.f; accz[k] = 0.f; accm[k] = 0.f; }
  int gotmask = 0;

#pragma unroll
  for (int dy = -2; dy <= 0; ++dy) {
    int cy = ny + dy;
    if (cy < 0) continue;
#pragma unroll
    for (int dx = -2; dx <= 0; ++dx) {
      int cx = nx + dx;
      if (cx < 0) continue;
      const int ox = -dx, oy = -dy;  // static after unroll
      int rowb = (cx << 14) | (cy << 7);

      int S[ZQ + 3];
#pragma unroll
      for (int j = 0; j < ZQ + 3; ++j)
        S[j] = start[rowb + min(max(zb0 + j, 0), N_GRID)];
#pragma unroll
      for (int k = 0; k < ZQ; ++k)
        gotmask |= (S[k + 3] > S[k]) ? (1 << k) : 0;

      for (int i = S[0]; i < S[ZQ + 2]; ++i) {
        const float4* src = pay + (size_t)i * 4;
        float4 q0 = src[0], q1 = src[1], q2 = src[2], q3 = src[3];

        float fx = q0.x * INV_DX - (float)cx;   // base_x == cx by construction
        float fy = q0.y * INV_DX - (float)cy;
        float gz = q0.z * INV_DX;
        float bzf = floorf(gz - 0.5f);
        float fz = gz - bzf;
        int oz0 = nz0 - (int)bzf;

        float wxy = wq(ox, fx) * wq(oy, fy);
        float dpx = ((float)ox - fx) * DX;
        float dpy = ((float)oy - fy) * DX;
        float wz0 = 0.5f * (1.5f - fz) * (1.5f - fz);
        float wz1 = 0.75f - (fz - 1.0f) * (fz - 1.0f);
        float wz2 = 0.5f * (fz - 0.5f) * (fz - 0.5f);

        // dpz-independent partial sums (shared across the quad's nodes)
        float sx = q0.w + q1.z * dpx + q1.w * dpy;
        float sy = q1.x + q2.y * dpx + q2.z * dpy;
        float sz = q1.y + q3.x * dpx + q3.y * dpy;
        float wm = wxy * P_MASS;

#pragma unroll
        for (int k = 0; k < ZQ; ++k) {
          int oz = oz0 + k;
          if (oz < 0 || oz > 2) continue;
          float wzz = (oz == 0) ? wz0 : ((oz == 1) ? wz1 : wz2);
          float w = wxy * wzz;
          float dpz = ((float)oz - fz) * DX;
          accx[k] += w * (sx + q2.x * dpz);
          accy[k] += w * (sy + q2.w * dpz);
          accz[k] += w * (sz + q3.z * dpz);
          accm[k] += wzz * wm;
        }
      }
    }
  }

  if (!gotmask) return;

  float4* g4 = (float4*)grid;
#pragma unroll
  for (int k = 0; k < ZQ; ++k) {
    int nz = nz0 + k;
    if (!((gotmask >> k) & 1) || nz > N_GRID - 1) continue;
    float m = accm[k];
    float ovx = 0.0f, ovy = 0.0f, ovz = 0.0f;
    if (m > 0.0f) {
      float inv = 1.0f / fmaxf(m, 1e-10f);
      ovx = accx[k] * inv;
      ovy = accy[k] * inv;
      ovz = accz[k] * inv;
      ovy -= DT * GRAVITY;
    }
    if (nx < BOUND && ovx < 0.0f) ovx = 0.0f;
    if (nx >= N_GRID - BOUND && ovx > 0.0f) ovx = 0.0f;
    if (ny < BOUND && ovy < 0.0f) ovy = 0.0f;
    if (ny >= N_GRID - BOUND && ovy > 0.0f) ovy = 0.0f;
    if (nz < BOUND && ovz < 0.0f) ovz = 0.0f;
    if (nz >= N_GRID - BOUND && ovz > 0.0f) ovz = 0.0f;
    g4[(nx << 14) | (ny << 7) | nz] = make_float4(ovx, ovy, ovz, m);
  }
}

// ---------------- G2P: gather grid velocity back to particles ----------------
__global__ __launch_bounds__(256) void mpm_g2p(
    const float* __restrict__ x, const float* __restrict__ F,
    const float* __restrict__ grid,
    float* __restrict__ out_x, float* __restrict__ out_v,
    float* __restrict__ out_C, float* __restrict__ out_F) {
  int n = blockIdx.x * blockDim.x + threadIdx.x;
  if (n >= N_PART) return;

  float px = x[n * 3 + 0], py = x[n * 3 + 1], pz = x[n * 3 + 2];
  float gx = px * INV_DX, gy = py * INV_DX, gz = pz * INV_DX;
  int bx = (int)floorf(gx - 0.5f);
  int by = (int)floorf(gy - 0.5f);
  int bz = (int)floorf(gz - 0.5f);
  float fx = gx - (float)bx, fy = gy - (float)by, fz = gz - (float)bz;

  float wx[3], wy[3], wz[3];
  wx[0] = 0.5f * (1.5f - fx) * (1.5f - fx);
  wx[1] = 0.75f - (fx - 1.0f) * (fx - 1.0f);
  wx[2] = 0.5f * (fx - 0.5f) * (fx - 0.5f);
  wy[0] = 0.5f * (1.5f - fy) * (1.5f - fy);
  wy[1] = 0.75f - (fy - 1.0f) * (fy - 1.0f);
  wy[2] = 0.5f * (fy - 0.5f) * (fy - 0.5f);
  wz[0] = 0.5f * (1.5f - fz) * (1.5f - fz);
  wz[1] = 0.75f - (fz - 1.0f) * (fz - 1.0f);
  wz[2] = 0.5f * (fz - 0.5f) * (fz - 0.5f);

  float vnx = 0.0f, vny = 0.0f, vnz = 0.0f;
  float Cn[9];
#pragma unroll
  for (int i = 0; i < 9; ++i) Cn[i] = 0.0f;

  const float4* g4 = (const float4*)grid;
#pragma unroll
  for (int a = 0; a < 3; ++a) {
#pragma unroll
    for (int bb = 0; bb < 3; ++bb) {
#pragma unroll
      for (int c = 0; c < 3; ++c) {
        float weight = wx[a] * wy[bb] * wz[c];
        float dpx = ((float)a - fx) * DX;
        float dpy = ((float)bb - fy) * DX;
        float dpz = ((float)c - fz) * DX;
        int nxg = min(max(bx + a, 0), N_GRID - 1);
        int nyg = min(max(by + bb, 0), N_GRID - 1);
        int nzg = min(max(bz + c, 0), N_GRID - 1);
        int flat = (nxg * N_GRID + nyg) * N_GRID + nzg;
        float4 g = g4[flat];
        vnx += weight * g.x;
        vny += weight * g.y;
        vnz += weight * g.z;
        Cn[0] += weight * g.x * dpx;
        Cn[1] += weight * g.x * dpy;
        Cn[2] += weight * g.x * dpz;
        Cn[3] += weight * g.y * dpx;
        Cn[4] += weight * g.y * dpy;
        Cn[5] += weight * g.y * dpz;
        Cn[6] += weight * g.z * dpx;
        Cn[7] += weight * g.z * dpy;
        Cn[8] += weight * g.z * dpz;
      }
    }
  }

#pragma unroll
  for (int i = 0; i < 9; ++i) Cn[i] *= C_SCALE;

  out_x[n * 3 + 0] = px + DT * vnx;
  out_x[n * 3 + 1] = py + DT * vny;
  out_x[n * 3 + 2] = pz + DT * vnz;
  out_v[n * 3 + 0] = vnx;
  out_v[n * 3 + 1] = vny;
  out_v[n * 3 + 2] = vnz;

  float A[9];
#pragma unroll
  for (int i = 0; i < 9; ++i) A[i] = DT * Cn[i];
  A[0] += 1.0f; A[4] += 1.0f; A[8] += 1.0f;

  float Fl[9];
#pragma unroll
  for (int i = 0; i < 9; ++i) Fl[i] = F[n * 9 + i];

#pragma unroll
  for (int i = 0; i < 3; ++i) {
#pragma unroll
    for (int k = 0; k < 3; ++k) {
      float s = A[i * 3 + 0] * Fl[0 * 3 + k] +
                A[i * 3 + 1] * Fl[1 * 3 + k] +
                A[i * 3 + 2] * Fl[2 * 3 + k];
      out_F[n * 9 + i * 3 + k] = s;
    }
  }

#pragma unroll
  for (int i = 0; i < 9; ++i) out_C[n * 9 + i] = Cn[i];
}

extern "C" void kernel_launch(void* const* d_in, const int* in_sizes, int n_in,
                              void* d_out, int out_size, void* d_ws, size_t ws_size,
                              hipStream_t stream) {
  const float* x      = (const float*)d_in[0];
  const float* v      = (const float*)d_in[1];
  const float* C      = (const float*)d_in[2];
  const float* F      = (const float*)d_in[3];
  const float* stress = (const float*)d_in[4];

  float* out = (float*)d_out;
  char*  ws  = (char*)d_ws;

  const size_t GRID_BYTES  = (size_t)N_GRID3 * 4 * sizeof(float);   // 33.5 MB
  const size_t PAY_BYTES   = (size_t)N_PART * 4 * sizeof(float4);   // 32 MB
  const size_t CNT_BYTES   = (size_t)N_GRID3 * sizeof(int);         // 8 MB
  const size_t START_BYTES = ((size_t)N_GRID3 + 1) * sizeof(int);   // 8 MB

  float*  grid   = (float*)ws;
  float4* pay    = (float4*)(ws + GRID_BYTES);
  int*    cnt    = (int*)(ws + GRID_BYTES + PAY_BYTES);             // doubles as cursor
  int*    startp = (int*)(ws + GRID_BYTES + PAY_BYTES + CNT_BYTES);
  int*    blkSum = (int*)(ws + GRID_BYTES + PAY_BYTES + CNT_BYTES + START_BYTES);
  int*    blkOff = blkSum + 2048;
  int*    bminP  = blkOff + 2048;
  int*    bmaxP  = bminP + 3;

  hipMemsetAsync(cnt, 0, CNT_BYTES, stream);
  hipMemsetAsync(bminP, 0x7F, 3 * sizeof(int), stream);  // large positive
  hipMemsetAsync(bmaxP, 0x00, 3 * sizeof(int), stream);  // cells are >= 0

  int pblocks = (N_PART + 255) / 256;
  k_count<<<pblocks, 256, 0, stream>>>(x, cnt, bminP, bmaxP);
  k_scan1<<<2048, 256, 0, stream>>>(cnt, blkSum);
  k_scan2<<<1, 256, 0, stream>>>(blkSum, blkOff, startp);
  k_scan3<<<2048, 256, 0, stream>>>(cnt, blkOff, startp);
  k_reorder<<<pblocks, 256, 0, stream>>>(x, v, C, stress, cnt, pay);

  // worst-case grid covers the full domain; threads with t >= vol exit at once
  mpm_p2g<<<(N_GRID3 / ZQ + 255) / 256, 256, 0, stream>>>(startp, pay, bminP, bmaxP, grid);

  float* out_x = out;
  float* out_v = out + (size_t)N_PART * 3;
  float* out_C = out + (size_t)N_PART * 6;
  float* out_F = out + (size_t)N_PART * 6 + (size_t)N_PART * 9;
  mpm_g2p<<<pblocks, 256, 0, stream>>>(x, F, grid, out_x, out_v, out_C, out_F);
}

// Round 8
// 229.839 us; speedup vs baseline: 3.2892x; 3.2892x over previous
//
#include <hip/hip_runtime.h>
#include <limits.h>

#define N_GRID 128
#define N_GRID3 (N_GRID * N_GRID * N_GRID)   // 2097152 cells/nodes

constexpr int   N_PART   = 500000;
constexpr float DT       = 0.0002f;
constexpr float DX       = 1.0f / 128.0f;
constexpr float INV_DX   = 128.0f;
constexpr float P_MASS   = 5.9604644775390625e-05f;   // (DX*0.5)^3 * 1000
constexpr float AFF_COEF = -7.8125e-07f;              // -DT * P_VOL * 4 * INV_DX^2
constexpr float GRAVITY  = 9.8f;
constexpr int   BOUND    = 3;
constexpr float C_SCALE  = 65536.0f;                  // 4 * INV_DX^2
constexpr int   ZQ       = 2;                         // z-nodes per p2g thread

// ---------------- pass 1: cell histogram + per-block bbox partials (no contended atomics) ----------------
__global__ __launch_bounds__(256) void k_count(const float* __restrict__ x,
                                               int* __restrict__ cnt,
                                               int* __restrict__ blkMin,
                                               int* __restrict__ blkMax) {
  __shared__ int lmin[12], lmax[12];  // 4 waves x 3 axes
  int n = blockIdx.x * 256 + threadIdx.x;
  int bx = INT_MAX, by = INT_MAX, bz = INT_MAX;
  int mx = -1, my = -1, mz = -1;
  if (n < N_PART) {
    bx = min(max((int)floorf(x[n * 3 + 0] * INV_DX - 0.5f), 0), N_GRID - 1);
    by = min(max((int)floorf(x[n * 3 + 1] * INV_DX - 0.5f), 0), N_GRID - 1);
    bz = min(max((int)floorf(x[n * 3 + 2] * INV_DX - 0.5f), 0), N_GRID - 1);
    int c = (bx << 14) | (by << 7) | bz;
    atomicAdd(&cnt[c], 1);  // 2M spread addresses: uncontended, native int atomic
    mx = bx; my = by; mz = bz;
  }
#pragma unroll
  for (int d = 32; d > 0; d >>= 1) {
    bx = min(bx, __shfl_xor(bx, d));
    by = min(by, __shfl_xor(by, d));
    bz = min(bz, __shfl_xor(bz, d));
    mx = max(mx, __shfl_xor(mx, d));
    my = max(my, __shfl_xor(my, d));
    mz = max(mz, __shfl_xor(mz, d));
  }
  int lane = threadIdx.x & 63, wid = threadIdx.x >> 6;
  if (lane == 0) {
    lmin[wid * 3 + 0] = bx; lmin[wid * 3 + 1] = by; lmin[wid * 3 + 2] = bz;
    lmax[wid * 3 + 0] = mx; lmax[wid * 3 + 1] = my; lmax[wid * 3 + 2] = mz;
  }
  __syncthreads();
  if (threadIdx.x == 0) {
    int b = blockIdx.x;
#pragma unroll
    for (int a = 0; a < 3; ++a) {
      blkMin[b * 3 + a] = min(min(lmin[a], lmin[3 + a]), min(lmin[6 + a], lmin[9 + a]));
      blkMax[b * 3 + a] = max(max(lmax[a], lmax[3 + a]), max(lmax[6 + a], lmax[9 + a]));
    }
  }
}

// ---------------- pass 2a: block sums (2048 blocks x 1024 bins) ----------------
__global__ __launch_bounds__(256) void k_scan1(const int* __restrict__ cnt,
                                               int* __restrict__ blkSum) {
  __shared__ int ws[4];
  int tid = threadIdx.x, lane = tid & 63, wid = tid >> 6;
  int4 v = ((const int4*)cnt)[blockIdx.x * 256 + tid];
  int s = v.x + v.y + v.z + v.w;
  for (int d = 32; d > 0; d >>= 1) s += __shfl_down(s, d);
  if (lane == 0) ws[wid] = s;
  __syncthreads();
  if (tid == 0) blkSum[blockIdx.x] = ws[0] + ws[1] + ws[2] + ws[3];
}

// ------- pass 2b: scan 2048 block sums + reduce bbox partials (1 workgroup) -------
__global__ __launch_bounds__(256) void k_scan2(const int* __restrict__ blkSum,
                                               int* __restrict__ blkOff,
                                               int* __restrict__ start,
                                               const int* __restrict__ blkMin,
                                               const int* __restrict__ blkMax,
                                               int nblkP,
                                               int* __restrict__ bbox) {
  __shared__ int wsum[4];
  __shared__ int rmin[12], rmax[12];
  int tid = threadIdx.x, lane = tid & 63, wid = tid >> 6;

  // --- scan part ---
  int base = tid * 8;
  int s[8], tot = 0;
#pragma unroll
  for (int j = 0; j < 8; ++j) { s[j] = blkSum[base + j]; tot += s[j]; }
  int incl = tot;
  for (int d = 1; d < 64; d <<= 1) {
    int t = __shfl_up(incl, d);
    if (lane >= d) incl += t;
  }
  if (lane == 63) wsum[wid] = incl;
  __syncthreads();
  int woff = 0;
  for (int w = 0; w < wid; ++w) woff += wsum[w];
  int run = woff + incl - tot;
#pragma unroll
  for (int j = 0; j < 8; ++j) { blkOff[base + j] = run; run += s[j]; }
  if (tid == 255) start[N_GRID3] = run;  // == N_PART

  // --- bbox reduce part (plain loads over nblkP partials) ---
  int bx = INT_MAX, by = INT_MAX, bz = INT_MAX;
  int mx = -1, my = -1, mz = -1;
  for (int j = tid; j < nblkP; j += 256) {
    bx = min(bx, blkMin[j * 3 + 0]);
    by = min(by, blkMin[j * 3 + 1]);
    bz = min(bz, blkMin[j * 3 + 2]);
    mx = max(mx, blkMax[j * 3 + 0]);
    my = max(my, blkMax[j * 3 + 1]);
    mz = max(mz, blkMax[j * 3 + 2]);
  }
#pragma unroll
  for (int d = 32; d > 0; d >>= 1) {
    bx = min(bx, __shfl_xor(bx, d));
    by = min(by, __shfl_xor(by, d));
    bz = min(bz, __shfl_xor(bz, d));
    mx = max(mx, __shfl_xor(mx, d));
    my = max(my, __shfl_xor(my, d));
    mz = max(mz, __shfl_xor(mz, d));
  }
  if (lane == 0) {
    rmin[wid * 3 + 0] = bx; rmin[wid * 3 + 1] = by; rmin[wid * 3 + 2] = bz;
    rmax[wid * 3 + 0] = mx; rmax[wid * 3 + 1] = my; rmax[wid * 3 + 2] = mz;
  }
  __syncthreads();
  if (tid == 0) {
#pragma unroll
    for (int a = 0; a < 3; ++a) {
      bbox[a]     = min(min(rmin[a], rmin[3 + a]), min(rmin[6 + a], rmin[9 + a]));
      bbox[3 + a] = max(max(rmax[a], rmax[3 + a]), max(rmax[6 + a], rmax[9 + a]));
    }
  }
}

// ------- pass 2c: in-block exclusive scan + offset; cursor written over cnt -------
__global__ __launch_bounds__(256) void k_scan3(int* __restrict__ cnt,
                                               const int* __restrict__ blkOff,
                                               int* __restrict__ start) {
  __shared__ int wsum[4];
  int tid = threadIdx.x, lane = tid & 63, wid = tid >> 6;
  int b = blockIdx.x;
  int4 v = ((const int4*)cnt)[b * 256 + tid];
  int s = v.x + v.y + v.z + v.w;
  int incl = s;
  for (int d = 1; d < 64; d <<= 1) {
    int t = __shfl_up(incl, d);
    if (lane >= d) incl += t;
  }
  if (lane == 63) wsum[wid] = incl;
  __syncthreads();
  int woff = blkOff[b];
  for (int w = 0; w < wid; ++w) woff += wsum[w];
  int run = woff + incl - s;
  int i0 = (b * 256 + tid) * 4;
  int r0 = run, r1 = r0 + v.x, r2 = r1 + v.y, r3 = r2 + v.z;
  start[i0 + 0] = r0; start[i0 + 1] = r1; start[i0 + 2] = r2; start[i0 + 3] = r3;
  cnt[i0 + 0] = r0; cnt[i0 + 1] = r1; cnt[i0 + 2] = r2; cnt[i0 + 3] = r3;  // cursor
}

// ---------------- pass 3: reorder + precompute 64B particle payload ----------------
__global__ __launch_bounds__(256) void k_reorder(
    const float* __restrict__ x, const float* __restrict__ v,
    const float* __restrict__ C, const float* __restrict__ S,
    int* __restrict__ cursor, float4* __restrict__ pay) {
  int n = blockIdx.x * 256 + threadIdx.x;
  if (n >= N_PART) return;

  float px = x[n * 3 + 0], py = x[n * 3 + 1], pz = x[n * 3 + 2];
  int bx = min(max((int)floorf(px * INV_DX - 0.5f), 0), N_GRID - 1);
  int by = min(max((int)floorf(py * INV_DX - 0.5f), 0), N_GRID - 1);
  int bz = min(max((int)floorf(pz * INV_DX - 0.5f), 0), N_GRID - 1);
  int c = (bx << 14) | (by << 7) | bz;
  int pos = atomicAdd(&cursor[c], 1);

  float mvx = P_MASS * v[n * 3 + 0];
  float mvy = P_MASS * v[n * 3 + 1];
  float mvz = P_MASS * v[n * 3 + 2];
  float aff[9];
#pragma unroll
  for (int k = 0; k < 9; ++k)
    aff[k] = AFF_COEF * S[n * 9 + k] + P_MASS * C[n * 9 + k];

  float4* dst = pay + (size_t)pos * 4;
  dst[0] = make_float4(px, py, pz, mvx);
  dst[1] = make_float4(mvy, mvz, aff[0], aff[1]);
  dst[2] = make_float4(aff[2], aff[3], aff[4], aff[5]);
  dst[3] = make_float4(aff[6], aff[7], aff[8], 0.0f);
}

// quadratic B-spline weight for static offset o (folds after unroll)
__device__ __forceinline__ float wq(int o, float f) {
  if (o == 0) return 0.5f * (1.5f - f) * (1.5f - f);
  if (o == 1) return 0.75f - (f - 1.0f) * (f - 1.0f);
  return 0.5f * (f - 0.5f) * (f - 0.5f);
}

// ---------------- P2G gather: dense bbox launch, ZQ z-nodes per thread ----------------
__global__ __launch_bounds__(256) void mpm_p2g(
    const int* __restrict__ start, const float4* __restrict__ pay,
    const int* __restrict__ bbox,
    float* __restrict__ grid /* [N_GRID3][4] final velocities */) {
  int bx0 = bbox[0], by0 = bbox[1], bz0c = bbox[2];
  int nxd = bbox[3] - bx0 + 3;   // nodes touched per axis = cells + 2
  int nyd = bbox[4] - by0 + 3;
  int nzd = bbox[5] - bz0c + 3;
  int dimzq = (nzd + ZQ - 1) / ZQ;
  int vol = nxd * nyd * dimzq;

  int t = blockIdx.x * 256 + threadIdx.x;
  if (t >= vol) return;
  int izq = t % dimzq;
  int r = t / dimzq;
  int iy = r % nyd;
  int ix = r / nyd;
  int nx = bx0 + ix, ny = by0 + iy, nz0 = bz0c + izq * ZQ;
  if (nx > N_GRID - 1 || ny > N_GRID - 1) return;
  int zb0 = nz0 - 2;  // first contributing cell

  float accx[ZQ], accy[ZQ], accz[ZQ], accm[ZQ];
#pragma unroll
  for (int k = 0; k < ZQ; ++k) { accx[k] = 0.f; accy[k] = 0.f; accz[k] = 0.f; accm[k] = 0.f; }
  int gotmask = 0;

#pragma unroll
  for (int dy = -2; dy <= 0; ++dy) {
    int cy = ny + dy;
    if (cy < 0) continue;
#pragma unroll
    for (int dx = -2; dx <= 0; ++dx) {
      int cx = nx + dx;
      if (cx < 0) continue;
      const int ox = -dx, oy = -dy;  // static after unroll
      int rowb = (cx << 14) | (cy << 7);

      int S[ZQ + 3];
#pragma unroll
      for (int j = 0; j < ZQ + 3; ++j)
        S[j] = start[rowb + min(max(zb0 + j, 0), N_GRID)];
#pragma unroll
      for (int k = 0; k < ZQ; ++k)
        gotmask |= (S[k + 3] > S[k]) ? (1 << k) : 0;

      for (int i = S[0]; i < S[ZQ + 2]; ++i) {
        const float4* src = pay + (size_t)i * 4;
        float4 q0 = src[0], q1 = src[1], q2 = src[2], q3 = src[3];

        float fx = q0.x * INV_DX - (float)cx;   // base_x == cx by construction
        float fy = q0.y * INV_DX - (float)cy;
        float gz = q0.z * INV_DX;
        float bzf = floorf(gz - 0.5f);
        float fz = gz - bzf;
        int oz0 = nz0 - (int)bzf;

        float wxy = wq(ox, fx) * wq(oy, fy);
        float dpx = ((float)ox - fx) * DX;
        float dpy = ((float)oy - fy) * DX;
        float wz0 = 0.5f * (1.5f - fz) * (1.5f - fz);
        float wz1 = 0.75f - (fz - 1.0f) * (fz - 1.0f);
        float wz2 = 0.5f * (fz - 0.5f) * (fz - 0.5f);

        float sx = q0.w + q1.z * dpx + q1.w * dpy;
        float sy = q1.x + q2.y * dpx + q2.z * dpy;
        float sz = q1.y + q3.x * dpx + q3.y * dpy;
        float wm = wxy * P_MASS;

#pragma unroll
        for (int k = 0; k < ZQ; ++k) {
          int oz = oz0 + k;
          if (oz < 0 || oz > 2) continue;
          float wzz = (oz == 0) ? wz0 : ((oz == 1) ? wz1 : wz2);
          float w = wxy * wzz;
          float dpz = ((float)oz - fz) * DX;
          accx[k] += w * (sx + q2.x * dpz);
          accy[k] += w * (sy + q2.w * dpz);
          accz[k] += w * (sz + q3.z * dpz);
          accm[k] += wzz * wm;
        }
      }
    }
  }

  if (!gotmask) return;

  float4* g4 = (float4*)grid;
#pragma unroll
  for (int k = 0; k < ZQ; ++k) {
    int nz = nz0 + k;
    if (!((gotmask >> k) & 1) || nz > N_GRID - 1) continue;
    float m = accm[k];
    float ovx = 0.0f, ovy = 0.0f, ovz = 0.0f;
    if (m > 0.0f) {
      float inv = 1.0f / fmaxf(m, 1e-10f);
      ovx = accx[k] * inv;
      ovy = accy[k] * inv;
      ovz = accz[k] * inv;
      ovy -= DT * GRAVITY;
    }
    if (nx < BOUND && ovx < 0.0f) ovx = 0.0f;
    if (nx >= N_GRID - BOUND && ovx > 0.0f) ovx = 0.0f;
    if (ny < BOUND && ovy < 0.0f) ovy = 0.0f;
    if (ny >= N_GRID - BOUND && ovy > 0.0f) ovy = 0.0f;
    if (nz < BOUND && ovz < 0.0f) ovz = 0.0f;
    if (nz >= N_GRID - BOUND && ovz > 0.0f) ovz = 0.0f;
    g4[(nx << 14) | (ny << 7) | nz] = make_float4(ovx, ovy, ovz, m);
  }
}

// ---------------- G2P: gather grid velocity back to particles ----------------
__global__ __launch_bounds__(256) void mpm_g2p(
    const float* __restrict__ x, const float* __restrict__ F,
    const float* __restrict__ grid,
    float* __restrict__ out_x, float* __restrict__ out_v,
    float* __restrict__ out_C, float* __restrict__ out_F) {
  int n = blockIdx.x * blockDim.x + threadIdx.x;
  if (n >= N_PART) return;

  float px = x[n * 3 + 0], py = x[n * 3 + 1], pz = x[n * 3 + 2];
  float gx = px * INV_DX, gy = py * INV_DX, gz = pz * INV_DX;
  int bx = (int)floorf(gx - 0.5f);
  int by = (int)floorf(gy - 0.5f);
  int bz = (int)floorf(gz - 0.5f);
  float fx = gx - (float)bx, fy = gy - (float)by, fz = gz - (float)bz;

  float wx[3], wy[3], wz[3];
  wx[0] = 0.5f * (1.5f - fx) * (1.5f - fx);
  wx[1] = 0.75f - (fx - 1.0f) * (fx - 1.0f);
  wx[2] = 0.5f * (fx - 0.5f) * (fx - 0.5f);
  wy[0] = 0.5f * (1.5f - fy) * (1.5f - fy);
  wy[1] = 0.75f - (fy - 1.0f) * (fy - 1.0f);
  wy[2] = 0.5f * (fy - 0.5f) * (fy - 0.5f);
  wz[0] = 0.5f * (1.5f - fz) * (1.5f - fz);
  wz[1] = 0.75f - (fz - 1.0f) * (fz - 1.0f);
  wz[2] = 0.5f * (fz - 0.5f) * (fz - 0.5f);

  float vnx = 0.0f, vny = 0.0f, vnz = 0.0f;
  float Cn[9];
#pragma unroll
  for (int i = 0; i < 9; ++i) Cn[i] = 0.0f;

  const float4* g4 = (const float4*)grid;
#pragma unroll
  for (int a = 0; a < 3; ++a) {
#pragma unroll
    for (int bb = 0; bb < 3; ++bb) {
#pragma unroll
      for (int c = 0; c < 3; ++c) {
        float weight = wx[a] * wy[bb] * wz[c];
        float dpx = ((float)a - fx) * DX;
        float dpy = ((float)bb - fy) * DX;
        float dpz = ((float)c - fz) * DX;
        int nxg = min(max(bx + a, 0), N_GRID - 1);
        int nyg = min(max(by + bb, 0), N_GRID - 1);
        int nzg = min(max(bz + c, 0), N_GRID - 1);
        int flat = (nxg * N_GRID + nyg) * N_GRID + nzg;
        float4 g = g4[flat];
        vnx += weight * g.x;
        vny += weight * g.y;
        vnz += weight * g.z;
        Cn[0] += weight * g.x * dpx;
        Cn[1] += weight * g.x * dpy;
        Cn[2] += weight * g.x * dpz;
        Cn[3] += weight * g.y * dpx;
        Cn[4] += weight * g.y * dpy;
        Cn[5] += weight * g.y * dpz;
        Cn[6] += weight * g.z * dpx;
        Cn[7] += weight * g.z * dpy;
        Cn[8] += weight * g.z * dpz;
      }
    }
  }

#pragma unroll
  for (int i = 0; i < 9; ++i) Cn[i] *= C_SCALE;

  out_x[n * 3 + 0] = px + DT * vnx;
  out_x[n * 3 + 1] = py + DT * vny;
  out_x[n * 3 + 2] = pz + DT * vnz;
  out_v[n * 3 + 0] = vnx;
  out_v[n * 3 + 1] = vny;
  out_v[n * 3 + 2] = vnz;

  float A[9];
#pragma unroll
  for (int i = 0; i < 9; ++i) A[i] = DT * Cn[i];
  A[0] += 1.0f; A[4] += 1.0f; A[8] += 1.0f;

  float Fl[9];
#pragma unroll
  for (int i = 0; i < 9; ++i) Fl[i] = F[n * 9 + i];

#pragma unroll
  for (int i = 0; i < 3; ++i) {
#pragma unroll
    for (int k = 0; k < 3; ++k) {
      float s = A[i * 3 + 0] * Fl[0 * 3 + k] +
                A[i * 3 + 1] * Fl[1 * 3 + k] +
                A[i * 3 + 2] * Fl[2 * 3 + k];
      out_F[n * 9 + i * 3 + k] = s;
    }
  }

#pragma unroll
  for (int i = 0; i < 9; ++i) out_C[n * 9 + i] = Cn[i];
}

extern "C" void kernel_launch(void* const* d_in, const int* in_sizes, int n_in,
                              void* d_out, int out_size, void* d_ws, size_t ws_size,
                              hipStream_t stream) {
  const float* x      = (const float*)d_in[0];
  const float* v      = (const float*)d_in[1];
  const float* C      = (const float*)d_in[2];
  const float* F      = (const float*)d_in[3];
  const float* stress = (const float*)d_in[4];

  float* out = (float*)d_out;
  char*  ws  = (char*)d_ws;

  const size_t GRID_BYTES  = (size_t)N_GRID3 * 4 * sizeof(float);   // 33.5 MB
  const size_t PAY_BYTES   = (size_t)N_PART * 4 * sizeof(float4);   // 32 MB
  const size_t CNT_BYTES   = (size_t)N_GRID3 * sizeof(int);         // 8 MB
  const size_t START_BYTES = ((size_t)N_GRID3 + 1) * sizeof(int);   // 8 MB

  int pblocks = (N_PART + 255) / 256;  // 1954

  float*  grid   = (float*)ws;
  float4* pay    = (float4*)(ws + GRID_BYTES);
  int*    cnt    = (int*)(ws + GRID_BYTES + PAY_BYTES);             // doubles as cursor
  int*    startp = (int*)(ws + GRID_BYTES + PAY_BYTES + CNT_BYTES);
  int*    blkSum = (int*)(ws + GRID_BYTES + PAY_BYTES + CNT_BYTES + START_BYTES);
  int*    blkOff = blkSum + 2048;
  int*    blkMin = blkOff + 2048;      // pblocks * 3
  int*    blkMax = blkMin + pblocks * 3;
  int*    bbox   = blkMax + pblocks * 3;  // 6 ints

  hipMemsetAsync(cnt, 0, CNT_BYTES, stream);

  k_count<<<pblocks, 256, 0, stream>>>(x, cnt, blkMin, blkMax);
  k_scan1<<<2048, 256, 0, stream>>>(cnt, blkSum);
  k_scan2<<<1, 256, 0, stream>>>(blkSum, blkOff, startp, blkMin, blkMax, pblocks, bbox);
  k_scan3<<<2048, 256, 0, stream>>>(cnt, blkOff, startp);
  k_reorder<<<pblocks, 256, 0, stream>>>(x, v, C, stress, cnt, pay);

  // worst-case grid covers the full domain; threads with t >= vol exit at once
  mpm_p2g<<<(N_GRID3 / ZQ + 255) / 256, 256, 0, stream>>>(startp, pay, bbox, grid);

  float* out_x = out;
  float* out_v = out + (size_t)N_PART * 3;
  float* out_C = out + (size_t)N_PART * 6;
  float* out_F = out + (size_t)N_PART * 6 + (size_t)N_PART * 9;
  mpm_g2p<<<pblocks, 256, 0, stream>>>(x, F, grid, out_x, out_v, out_C, out_F);
}

// Round 9
// 228.748 us; speedup vs baseline: 3.3049x; 1.0048x over previous
//
#include <hip/hip_runtime.h>
#include <limits.h>

#define N_GRID 128
#define N_GRID3 (N_GRID * N_GRID * N_GRID)   // 2097152 cells/nodes

constexpr int   N_PART   = 500000;
constexpr float DT       = 0.0002f;
constexpr float DX       = 1.0f / 128.0f;
constexpr float INV_DX   = 128.0f;
constexpr float P_MASS   = 5.9604644775390625e-05f;   // (DX*0.5)^3 * 1000
constexpr float AFF_COEF = -7.8125e-07f;              // -DT * P_VOL * 4 * INV_DX^2
constexpr float GRAVITY  = 9.8f;
constexpr int   BOUND    = 3;
constexpr float C_SCALE  = 65536.0f;                  // 4 * INV_DX^2
constexpr int   ZQ       = 2;                         // z-nodes per p2g thread
constexpr int   NXCD     = 8;

// ---------------- pass 1: cell histogram + per-block bbox partials ----------------
__global__ __launch_bounds__(256) void k_count(const float* __restrict__ x,
                                               int* __restrict__ cnt,
                                               int* __restrict__ blkMin,
                                               int* __restrict__ blkMax) {
  __shared__ int lmin[12], lmax[12];  // 4 waves x 3 axes
  int n = blockIdx.x * 256 + threadIdx.x;
  int bx = INT_MAX, by = INT_MAX, bz = INT_MAX;
  int mx = -1, my = -1, mz = -1;
  if (n < N_PART) {
    bx = min(max((int)floorf(x[n * 3 + 0] * INV_DX - 0.5f), 0), N_GRID - 1);
    by = min(max((int)floorf(x[n * 3 + 1] * INV_DX - 0.5f), 0), N_GRID - 1);
    bz = min(max((int)floorf(x[n * 3 + 2] * INV_DX - 0.5f), 0), N_GRID - 1);
    int c = (bx << 14) | (by << 7) | bz;
    atomicAdd(&cnt[c], 1);  // 2M spread addresses: uncontended
    mx = bx; my = by; mz = bz;
  }
#pragma unroll
  for (int d = 32; d > 0; d >>= 1) {
    bx = min(bx, __shfl_xor(bx, d));
    by = min(by, __shfl_xor(by, d));
    bz = min(bz, __shfl_xor(bz, d));
    mx = max(mx, __shfl_xor(mx, d));
    my = max(my, __shfl_xor(my, d));
    mz = max(mz, __shfl_xor(mz, d));
  }
  int lane = threadIdx.x & 63, wid = threadIdx.x >> 6;
  if (lane == 0) {
    lmin[wid * 3 + 0] = bx; lmin[wid * 3 + 1] = by; lmin[wid * 3 + 2] = bz;
    lmax[wid * 3 + 0] = mx; lmax[wid * 3 + 1] = my; lmax[wid * 3 + 2] = mz;
  }
  __syncthreads();
  if (threadIdx.x == 0) {
    int b = blockIdx.x;
#pragma unroll
    for (int a = 0; a < 3; ++a) {
      blkMin[b * 3 + a] = min(min(lmin[a], lmin[3 + a]), min(lmin[6 + a], lmin[9 + a]));
      blkMax[b * 3 + a] = max(max(lmax[a], lmax[3 + a]), max(lmax[6 + a], lmax[9 + a]));
    }
  }
}

// ---------------- pass 2a: block sums (2048 blocks x 1024 bins) ----------------
__global__ __launch_bounds__(256) void k_scan1(const int* __restrict__ cnt,
                                               int* __restrict__ blkSum) {
  __shared__ int ws[4];
  int tid = threadIdx.x, lane = tid & 63, wid = tid >> 6;
  int4 v = ((const int4*)cnt)[blockIdx.x * 256 + tid];
  int s = v.x + v.y + v.z + v.w;
  for (int d = 32; d > 0; d >>= 1) s += __shfl_down(s, d);
  if (lane == 0) ws[wid] = s;
  __syncthreads();
  if (tid == 0) blkSum[blockIdx.x] = ws[0] + ws[1] + ws[2] + ws[3];
}

// ------- pass 2b: scan 2048 block sums + reduce bbox partials (1 workgroup) -------
__global__ __launch_bounds__(256) void k_scan2(const int* __restrict__ blkSum,
                                               int* __restrict__ blkOff,
                                               int* __restrict__ start,
                                               const int* __restrict__ blkMin,
                                               const int* __restrict__ blkMax,
                                               int nblkP,
                                               int* __restrict__ bbox) {
  __shared__ int wsum[4];
  __shared__ int rmin[12], rmax[12];
  int tid = threadIdx.x, lane = tid & 63, wid = tid >> 6;

  int base = tid * 8;
  int s[8], tot = 0;
#pragma unroll
  for (int j = 0; j < 8; ++j) { s[j] = blkSum[base + j]; tot += s[j]; }
  int incl = tot;
  for (int d = 1; d < 64; d <<= 1) {
    int t = __shfl_up(incl, d);
    if (lane >= d) incl += t;
  }
  if (lane == 63) wsum[wid] = incl;
  __syncthreads();
  int woff = 0;
  for (int w = 0; w < wid; ++w) woff += wsum[w];
  int run = woff + incl - tot;
#pragma unroll
  for (int j = 0; j < 8; ++j) { blkOff[base + j] = run; run += s[j]; }
  if (tid == 255) start[N_GRID3] = run;  // == N_PART

  int bx = INT_MAX, by = INT_MAX, bz = INT_MAX;
  int mx = -1, my = -1, mz = -1;
  for (int j = tid; j < nblkP; j += 256) {
    bx = min(bx, blkMin[j * 3 + 0]);
    by = min(by, blkMin[j * 3 + 1]);
    bz = min(bz, blkMin[j * 3 + 2]);
    mx = max(mx, blkMax[j * 3 + 0]);
    my = max(my, blkMax[j * 3 + 1]);
    mz = max(mz, blkMax[j * 3 + 2]);
  }
#pragma unroll
  for (int d = 32; d > 0; d >>= 1) {
    bx = min(bx, __shfl_xor(bx, d));
    by = min(by, __shfl_xor(by, d));
    bz = min(bz, __shfl_xor(bz, d));
    mx = max(mx, __shfl_xor(mx, d));
    my = max(my, __shfl_xor(my, d));
    mz = max(mz, __shfl_xor(mz, d));
  }
  if (lane == 0) {
    rmin[wid * 3 + 0] = bx; rmin[wid * 3 + 1] = by; rmin[wid * 3 + 2] = bz;
    rmax[wid * 3 + 0] = mx; rmax[wid * 3 + 1] = my; rmax[wid * 3 + 2] = mz;
  }
  __syncthreads();
  if (tid == 0) {
#pragma unroll
    for (int a = 0; a < 3; ++a) {
      bbox[a]     = min(min(rmin[a], rmin[3 + a]), min(rmin[6 + a], rmin[9 + a]));
      bbox[3 + a] = max(max(rmax[a], rmax[3 + a]), max(rmax[6 + a], rmax[9 + a]));
    }
  }
}

// ------- pass 2c: in-block exclusive scan + offset; cursor written over cnt -------
__global__ __launch_bounds__(256) void k_scan3(int* __restrict__ cnt,
                                               const int* __restrict__ blkOff,
                                               int* __restrict__ start) {
  __shared__ int wsum[4];
  int tid = threadIdx.x, lane = tid & 63, wid = tid >> 6;
  int b = blockIdx.x;
  int4 v = ((const int4*)cnt)[b * 256 + tid];
  int s = v.x + v.y + v.z + v.w;
  int incl = s;
  for (int d = 1; d < 64; d <<= 1) {
    int t = __shfl_up(incl, d);
    if (lane >= d) incl += t;
  }
  if (lane == 63) wsum[wid] = incl;
  __syncthreads();
  int woff = blkOff[b];
  for (int w = 0; w < wid; ++w) woff += wsum[w];
  int run = woff + incl - s;
  int i0 = (b * 256 + tid) * 4;
  int r0 = run, r1 = r0 + v.x, r2 = r1 + v.y, r3 = r2 + v.z;
  start[i0 + 0] = r0; start[i0 + 1] = r1; start[i0 + 2] = r2; start[i0 + 3] = r3;
  cnt[i0 + 0] = r0; cnt[i0 + 1] = r1; cnt[i0 + 2] = r2; cnt[i0 + 3] = r3;  // cursor
}

// ---------------- pass 3: reorder + precompute 64B particle payload ----------------
__global__ __launch_bounds__(256) void k_reorder(
    const float* __restrict__ x, const float* __restrict__ v,
    const float* __restrict__ C, const float* __restrict__ S,
    int* __restrict__ cursor, float4* __restrict__ pay) {
  int n = blockIdx.x * 256 + threadIdx.x;
  if (n >= N_PART) return;

  float px = x[n * 3 + 0], py = x[n * 3 + 1], pz = x[n * 3 + 2];
  int bx = min(max((int)floorf(px * INV_DX - 0.5f), 0), N_GRID - 1);
  int by = min(max((int)floorf(py * INV_DX - 0.5f), 0), N_GRID - 1);
  int bz = min(max((int)floorf(pz * INV_DX - 0.5f), 0), N_GRID - 1);
  int c = (bx << 14) | (by << 7) | bz;
  int pos = atomicAdd(&cursor[c], 1);

  float mvx = P_MASS * v[n * 3 + 0];
  float mvy = P_MASS * v[n * 3 + 1];
  float mvz = P_MASS * v[n * 3 + 2];
  float aff[9];
#pragma unroll
  for (int k = 0; k < 9; ++k)
    aff[k] = AFF_COEF * S[n * 9 + k] + P_MASS * C[n * 9 + k];

  float4* dst = pay + (size_t)pos * 4;
  dst[0] = make_float4(px, py, pz, mvx);
  dst[1] = make_float4(mvy, mvz, aff[0], aff[1]);
  dst[2] = make_float4(aff[2], aff[3], aff[4], aff[5]);
  dst[3] = make_float4(aff[6], aff[7], aff[8], 0.0f);
}

// quadratic B-spline weight for static offset o (folds after unroll)
__device__ __forceinline__ float wq(int o, float f) {
  if (o == 0) return 0.5f * (1.5f - f) * (1.5f - f);
  if (o == 1) return 0.75f - (f - 1.0f) * (f - 1.0f);
  return 0.5f * (f - 0.5f) * (f - 0.5f);
}

// ---------------- P2G gather: dense bbox launch + bijective XCD swizzle ----------------
// Consecutive hardware blocks round-robin across XCDs; the m204 bijection gives
// each XCD a CONTIGUOUS chunk of the active block range, so neighboring (ix,iy)
// blocks (which re-read the same particle columns) share one L2.
__global__ __launch_bounds__(256) void mpm_p2g(
    const int* __restrict__ start, const float4* __restrict__ pay,
    const int* __restrict__ bbox,
    float* __restrict__ grid /* [N_GRID3][4] final velocities */) {
  int bx0 = bbox[0], by0 = bbox[1], bz0c = bbox[2];
  int nxd = bbox[3] - bx0 + 3;   // nodes touched per axis = cells + 2
  int nyd = bbox[4] - by0 + 3;
  int nzd = bbox[5] - bz0c + 3;
  int dimzq = (nzd + ZQ - 1) / ZQ;
  int vol = nxd * nyd * dimzq;
  int nact = (vol + 255) >> 8;          // active blocks

  int bid = blockIdx.x;
  if (bid >= nact) return;
  // bijective XCD swizzle (m204): xcd = bid % 8 owns a contiguous wgid chunk
  int q = nact >> 3, r = nact & 7;
  int xcd = bid & 7, sub = bid >> 3;
  int wgid = (xcd < r ? xcd * (q + 1) : r * (q + 1) + (xcd - r) * q) + sub;

  int t = wgid * 256 + (int)threadIdx.x;
  if (t >= vol) return;
  int izq = t % dimzq;
  int rr = t / dimzq;
  int iy = rr % nyd;
  int ix = rr / nyd;
  int nx = bx0 + ix, ny = by0 + iy, nz0 = bz0c + izq * ZQ;
  if (nx > N_GRID - 1 || ny > N_GRID - 1) return;
  int zb0 = nz0 - 2;  // first contributing cell

  float accx[ZQ], accy[ZQ], accz[ZQ], accm[ZQ];
#pragma unroll
  for (int k = 0; k < ZQ; ++k) { accx[k] = 0.f; accy[k] = 0.f; accz[k] = 0.f; accm[k] = 0.f; }
  int gotmask = 0;

#pragma unroll
  for (int dy = -2; dy <= 0; ++dy) {
    int cy = ny + dy;
    if (cy < 0) continue;
#pragma unroll
    for (int dx = -2; dx <= 0; ++dx) {
      int cx = nx + dx;
      if (cx < 0) continue;
      const int ox = -dx, oy = -dy;  // static after unroll
      int rowb = (cx << 14) | (cy << 7);

      int S[ZQ + 3];
#pragma unroll
      for (int j = 0; j < ZQ + 3; ++j)
        S[j] = start[rowb + min(max(zb0 + j, 0), N_GRID)];
#pragma unroll
      for (int k = 0; k < ZQ; ++k)
        gotmask |= (S[k + 3] > S[k]) ? (1 << k) : 0;

      for (int i = S[0]; i < S[ZQ + 2]; ++i) {
        const float4* src = pay + (size_t)i * 4;
        float4 q0 = src[0], q1 = src[1], q2 = src[2], q3 = src[3];

        float fx = q0.x * INV_DX - (float)cx;   // base_x == cx by construction
        float fy = q0.y * INV_DX - (float)cy;
        float gz = q0.z * INV_DX;
        float bzf = floorf(gz - 0.5f);
        float fz = gz - bzf;
        int oz0 = nz0 - (int)bzf;

        float wxy = wq(ox, fx) * wq(oy, fy);
        float dpx = ((float)ox - fx) * DX;
        float dpy = ((float)oy - fy) * DX;
        float wz0 = 0.5f * (1.5f - fz) * (1.5f - fz);
        float wz1 = 0.75f - (fz - 1.0f) * (fz - 1.0f);
        float wz2 = 0.5f * (fz - 0.5f) * (fz - 0.5f);

        float sx = q0.w + q1.z * dpx + q1.w * dpy;
        float sy = q1.x + q2.y * dpx + q2.z * dpy;
        float sz = q1.y + q3.x * dpx + q3.y * dpy;
        float wm = wxy * P_MASS;

#pragma unroll
        for (int k = 0; k < ZQ; ++k) {
          int oz = oz0 + k;
          if (oz < 0 || oz > 2) continue;
          float wzz = (oz == 0) ? wz0 : ((oz == 1) ? wz1 : wz2);
          float w = wxy * wzz;
          float dpz = ((float)oz - fz) * DX;
          accx[k] += w * (sx + q2.x * dpz);
          accy[k] += w * (sy + q2.w * dpz);
          accz[k] += w * (sz + q3.z * dpz);
          accm[k] += wzz * wm;
        }
      }
    }
  }

  if (!gotmask) return;

  float4* g4 = (float4*)grid;
#pragma unroll
  for (int k = 0; k < ZQ; ++k) {
    int nz = nz0 + k;
    if (!((gotmask >> k) & 1) || nz > N_GRID - 1) continue;
    float m = accm[k];
    float ovx = 0.0f, ovy = 0.0f, ovz = 0.0f;
    if (m > 0.0f) {
      float inv = 1.0f / fmaxf(m, 1e-10f);
      ovx = accx[k] * inv;
      ovy = accy[k] * inv;
      ovz = accz[k] * inv;
      ovy -= DT * GRAVITY;
    }
    if (nx < BOUND && ovx < 0.0f) ovx = 0.0f;
    if (nx >= N_GRID - BOUND && ovx > 0.0f) ovx = 0.0f;
    if (ny < BOUND && ovy < 0.0f) ovy = 0.0f;
    if (ny >= N_GRID - BOUND && ovy > 0.0f) ovy = 0.0f;
    if (nz < BOUND && ovz < 0.0f) ovz = 0.0f;
    if (nz >= N_GRID - BOUND && ovz > 0.0f) ovz = 0.0f;
    g4[(nx << 14) | (ny << 7) | nz] = make_float4(ovx, ovy, ovz, m);
  }
}

// ---------------- G2P: gather grid velocity back to particles ----------------
__global__ __launch_bounds__(256) void mpm_g2p(
    const float* __restrict__ x, const float* __restrict__ F,
    const float* __restrict__ grid,
    float* __restrict__ out_x, float* __restrict__ out_v,
    float* __restrict__ out_C, float* __restrict__ out_F) {
  int n = blockIdx.x * blockDim.x + threadIdx.x;
  if (n >= N_PART) return;

  float px = x[n * 3 + 0], py = x[n * 3 + 1], pz = x[n * 3 + 2];
  float gx = px * INV_DX, gy = py * INV_DX, gz = pz * INV_DX;
  int bx = (int)floorf(gx - 0.5f);
  int by = (int)floorf(gy - 0.5f);
  int bz = (int)floorf(gz - 0.5f);
  float fx = gx - (float)bx, fy = gy - (float)by, fz = gz - (float)bz;

  float wx[3], wy[3], wz[3];
  wx[0] = 0.5f * (1.5f - fx) * (1.5f - fx);
  wx[1] = 0.75f - (fx - 1.0f) * (fx - 1.0f);
  wx[2] = 0.5f * (fx - 0.5f) * (fx - 0.5f);
  wy[0] = 0.5f * (1.5f - fy) * (1.5f - fy);
  wy[1] = 0.75f - (fy - 1.0f) * (fy - 1.0f);
  wy[2] = 0.5f * (fy - 0.5f) * (fy - 0.5f);
  wz[0] = 0.5f * (1.5f - fz) * (1.5f - fz);
  wz[1] = 0.75f - (fz - 1.0f) * (fz - 1.0f);
  wz[2] = 0.5f * (fz - 0.5f) * (fz - 0.5f);

  float vnx = 0.0f, vny = 0.0f, vnz = 0.0f;
  float Cn[9];
#pragma unroll
  for (int i = 0; i < 9; ++i) Cn[i] = 0.0f;

  const float4* g4 = (const float4*)grid;
#pragma unroll
  for (int a = 0; a < 3; ++a) {
#pragma unroll
    for (int bb = 0; bb < 3; ++bb) {
#pragma unroll
      for (int c = 0; c < 3; ++c) {
        float weight = wx[a] * wy[bb] * wz[c];
        float dpx = ((float)a - fx) * DX;
        float dpy = ((float)bb - fy) * DX;
        float dpz = ((float)c - fz) * DX;
        int nxg = min(max(bx + a, 0), N_GRID - 1);
        int nyg = min(max(by + bb, 0), N_GRID - 1);
        int nzg = min(max(bz + c, 0), N_GRID - 1);
        int flat = (nxg * N_GRID + nyg) * N_GRID + nzg;
        float4 g = g4[flat];
        vnx += weight * g.x;
        vny += weight * g.y;
        vnz += weight * g.z;
        Cn[0] += weight * g.x * dpx;
        Cn[1] += weight * g.x * dpy;
        Cn[2] += weight * g.x * dpz;
        Cn[3] += weight * g.y * dpx;
        Cn[4] += weight * g.y * dpy;
        Cn[5] += weight * g.y * dpz;
        Cn[6] += weight * g.z * dpx;
        Cn[7] += weight * g.z * dpy;
        Cn[8] += weight * g.z * dpz;
      }
    }
  }

#pragma unroll
  for (int i = 0; i < 9; ++i) Cn[i] *= C_SCALE;

  out_x[n * 3 + 0] = px + DT * vnx;
  out_x[n * 3 + 1] = py + DT * vny;
  out_x[n * 3 + 2] = pz + DT * vnz;
  out_v[n * 3 + 0] = vnx;
  out_v[n * 3 + 1] = vny;
  out_v[n * 3 + 2] = vnz;

  float A[9];
#pragma unroll
  for (int i = 0; i < 9; ++i) A[i] = DT * Cn[i];
  A[0] += 1.0f; A[4] += 1.0f; A[8] += 1.0f;

  float Fl[9];
#pragma unroll
  for (int i = 0; i < 9; ++i) Fl[i] = F[n * 9 + i];

#pragma unroll
  for (int i = 0; i < 3; ++i) {
#pragma unroll
    for (int k = 0; k < 3; ++k) {
      float s = A[i * 3 + 0] * Fl[0 * 3 + k] +
                A[i * 3 + 1] * Fl[1 * 3 + k] +
                A[i * 3 + 2] * Fl[2 * 3 + k];
      out_F[n * 9 + i * 3 + k] = s;
    }
  }

#pragma unroll
  for (int i = 0; i < 9; ++i) out_C[n * 9 + i] = Cn[i];
}

extern "C" void kernel_launch(void* const* d_in, const int* in_sizes, int n_in,
                              void* d_out, int out_size, void* d_ws, size_t ws_size,
                              hipStream_t stream) {
  const float* x      = (const float*)d_in[0];
  const float* v      = (const float*)d_in[1];
  const float* C      = (const float*)d_in[2];
  const float* F      = (const float*)d_in[3];
  const float* stress = (const float*)d_in[4];

  float* out = (float*)d_out;
  char*  ws  = (char*)d_ws;

  const size_t GRID_BYTES  = (size_t)N_GRID3 * 4 * sizeof(float);   // 33.5 MB
  const size_t PAY_BYTES   = (size_t)N_PART * 4 * sizeof(float4);   // 32 MB
  const size_t CNT_BYTES   = (size_t)N_GRID3 * sizeof(int);         // 8 MB
  const size_t START_BYTES = ((size_t)N_GRID3 + 1) * sizeof(int);   // 8 MB

  int pblocks = (N_PART + 255) / 256;  // 1954

  float*  grid   = (float*)ws;
  float4* pay    = (float4*)(ws + GRID_BYTES);
  int*    cnt    = (int*)(ws + GRID_BYTES + PAY_BYTES);             // doubles as cursor
  int*    startp = (int*)(ws + GRID_BYTES + PAY_BYTES + CNT_BYTES);
  int*    blkSum = (int*)(ws + GRID_BYTES + PAY_BYTES + CNT_BYTES + START_BYTES);
  int*    blkOff = blkSum + 2048;
  int*    blkMin = blkOff + 2048;      // pblocks * 3
  int*    blkMax = blkMin + pblocks * 3;
  int*    bbox   = blkMax + pblocks * 3;  // 6 ints

  hipMemsetAsync(cnt, 0, CNT_BYTES, stream);

  k_count<<<pblocks, 256, 0, stream>>>(x, cnt, blkMin, blkMax);
  k_scan1<<<2048, 256, 0, stream>>>(cnt, blkSum);
  k_scan2<<<1, 256, 0, stream>>>(blkSum, blkOff, startp, blkMin, blkMax, pblocks, bbox);
  k_scan3<<<2048, 256, 0, stream>>>(cnt, blkOff, startp);
  k_reorder<<<pblocks, 256, 0, stream>>>(x, v, C, stress, cnt, pay);

  // worst-case grid covers the full domain; swizzle + exits handled in-kernel
  mpm_p2g<<<(N_GRID3 / ZQ + 255) / 256, 256, 0, stream>>>(startp, pay, bbox, grid);

  float* out_x = out;
  float* out_v = out + (size_t)N_PART * 3;
  float* out_C = out + (size_t)N_PART * 6;
  float* out_F = out + (size_t)N_PART * 6 + (size_t)N_PART * 9;
  mpm_g2p<<<pblocks, 256, 0, stream>>>(x, F, grid, out_x, out_v, out_C, out_F);
}

// Round 10
// 201.555 us; speedup vs baseline: 3.7508x; 1.1349x over previous
//
#include <hip/hip_runtime.h>
#include <limits.h>

#define N_GRID 128
#define N_GRID3 (N_GRID * N_GRID * N_GRID)   // 2097152 cells/nodes

constexpr int   N_PART   = 500000;
constexpr float DT       = 0.0002f;
constexpr float DX       = 1.0f / 128.0f;
constexpr float INV_DX   = 128.0f;
constexpr float P_MASS   = 5.9604644775390625e-05f;   // (DX*0.5)^3 * 1000
constexpr float AFF_COEF = -7.8125e-07f;              // -DT * P_VOL * 4 * INV_DX^2
constexpr float GRAVITY  = 9.8f;
constexpr int   BOUND    = 3;
constexpr float C_SCALE  = 65536.0f;                  // 4 * INV_DX^2
constexpr int   ZQ       = 2;                         // z-nodes per p2g thread

// ---------------- pass 1: cell histogram + per-block bbox partials ----------------
__global__ __launch_bounds__(256) void k_count(const float* __restrict__ x,
                                               int* __restrict__ cnt,
                                               int* __restrict__ blkMin,
                                               int* __restrict__ blkMax) {
  __shared__ int lmin[12], lmax[12];  // 4 waves x 3 axes
  int n = blockIdx.x * 256 + threadIdx.x;
  int bx = INT_MAX, by = INT_MAX, bz = INT_MAX;
  int mx = -1, my = -1, mz = -1;
  if (n < N_PART) {
    bx = min(max((int)floorf(x[n * 3 + 0] * INV_DX - 0.5f), 0), N_GRID - 1);
    by = min(max((int)floorf(x[n * 3 + 1] * INV_DX - 0.5f), 0), N_GRID - 1);
    bz = min(max((int)floorf(x[n * 3 + 2] * INV_DX - 0.5f), 0), N_GRID - 1);
    int c = (bx << 14) | (by << 7) | bz;
    atomicAdd(&cnt[c], 1);  // 2M spread addresses: uncontended
    mx = bx; my = by; mz = bz;
  }
#pragma unroll
  for (int d = 32; d > 0; d >>= 1) {
    bx = min(bx, __shfl_xor(bx, d));
    by = min(by, __shfl_xor(by, d));
    bz = min(bz, __shfl_xor(bz, d));
    mx = max(mx, __shfl_xor(mx, d));
    my = max(my, __shfl_xor(my, d));
    mz = max(mz, __shfl_xor(mz, d));
  }
  int lane = threadIdx.x & 63, wid = threadIdx.x >> 6;
  if (lane == 0) {
    lmin[wid * 3 + 0] = bx; lmin[wid * 3 + 1] = by; lmin[wid * 3 + 2] = bz;
    lmax[wid * 3 + 0] = mx; lmax[wid * 3 + 1] = my; lmax[wid * 3 + 2] = mz;
  }
  __syncthreads();
  if (threadIdx.x == 0) {
    int b = blockIdx.x;
#pragma unroll
    for (int a = 0; a < 3; ++a) {
      blkMin[b * 3 + a] = min(min(lmin[a], lmin[3 + a]), min(lmin[6 + a], lmin[9 + a]));
      blkMax[b * 3 + a] = max(max(lmax[a], lmax[3 + a]), max(lmax[6 + a], lmax[9 + a]));
    }
  }
}

// ---------------- pass 2a: block sums (2048 blocks x 1024 bins) ----------------
__global__ __launch_bounds__(256) void k_scan1(const int* __restrict__ cnt,
                                               int* __restrict__ blkSum) {
  __shared__ int ws[4];
  int tid = threadIdx.x, lane = tid & 63, wid = tid >> 6;
  int4 v = ((const int4*)cnt)[blockIdx.x * 256 + tid];
  int s = v.x + v.y + v.z + v.w;
  for (int d = 32; d > 0; d >>= 1) s += __shfl_down(s, d);
  if (lane == 0) ws[wid] = s;
  __syncthreads();
  if (tid == 0) blkSum[blockIdx.x] = ws[0] + ws[1] + ws[2] + ws[3];
}

// ------- pass 2b: scan 2048 block sums + reduce bbox partials (1 workgroup) -------
__global__ __launch_bounds__(256) void k_scan2(const int* __restrict__ blkSum,
                                               int* __restrict__ blkOff,
                                               int* __restrict__ start,
                                               const int* __restrict__ blkMin,
                                               const int* __restrict__ blkMax,
                                               int nblkP,
                                               int* __restrict__ bbox) {
  __shared__ int wsum[4];
  __shared__ int rmin[12], rmax[12];
  int tid = threadIdx.x, lane = tid & 63, wid = tid >> 6;

  int base = tid * 8;
  int s[8], tot = 0;
#pragma unroll
  for (int j = 0; j < 8; ++j) { s[j] = blkSum[base + j]; tot += s[j]; }
  int incl = tot;
  for (int d = 1; d < 64; d <<= 1) {
    int t = __shfl_up(incl, d);
    if (lane >= d) incl += t;
  }
  if (lane == 63) wsum[wid] = incl;
  __syncthreads();
  int woff = 0;
  for (int w = 0; w < wid; ++w) woff += wsum[w];
  int run = woff + incl - tot;
#pragma unroll
  for (int j = 0; j < 8; ++j) { blkOff[base + j] = run; run += s[j]; }
  if (tid == 255) start[N_GRID3] = run;  // == N_PART

  int bx = INT_MAX, by = INT_MAX, bz = INT_MAX;
  int mx = -1, my = -1, mz = -1;
  for (int j = tid; j < nblkP; j += 256) {
    bx = min(bx, blkMin[j * 3 + 0]);
    by = min(by, blkMin[j * 3 + 1]);
    bz = min(bz, blkMin[j * 3 + 2]);
    mx = max(mx, blkMax[j * 3 + 0]);
    my = max(my, blkMax[j * 3 + 1]);
    mz = max(mz, blkMax[j * 3 + 2]);
  }
#pragma unroll
  for (int d = 32; d > 0; d >>= 1) {
    bx = min(bx, __shfl_xor(bx, d));
    by = min(by, __shfl_xor(by, d));
    bz = min(bz, __shfl_xor(bz, d));
    mx = max(mx, __shfl_xor(mx, d));
    my = max(my, __shfl_xor(my, d));
    mz = max(mz, __shfl_xor(mz, d));
  }
  if (lane == 0) {
    rmin[wid * 3 + 0] = bx; rmin[wid * 3 + 1] = by; rmin[wid * 3 + 2] = bz;
    rmax[wid * 3 + 0] = mx; rmax[wid * 3 + 1] = my; rmax[wid * 3 + 2] = mz;
  }
  __syncthreads();
  if (tid == 0) {
#pragma unroll
    for (int a = 0; a < 3; ++a) {
      bbox[a]     = min(min(rmin[a], rmin[3 + a]), min(rmin[6 + a], rmin[9 + a]));
      bbox[3 + a] = max(max(rmax[a], rmax[3 + a]), max(rmax[6 + a], rmax[9 + a]));
    }
  }
}

// ------- pass 2c: in-block exclusive scan + offset; cursor written over cnt -------
__global__ __launch_bounds__(256) void k_scan3(int* __restrict__ cnt,
                                               const int* __restrict__ blkOff,
                                               int* __restrict__ start) {
  __shared__ int wsum[4];
  int tid = threadIdx.x, lane = tid & 63, wid = tid >> 6;
  int b = blockIdx.x;
  int4 v = ((const int4*)cnt)[b * 256 + tid];
  int s = v.x + v.y + v.z + v.w;
  int incl = s;
  for (int d = 1; d < 64; d <<= 1) {
    int t = __shfl_up(incl, d);
    if (lane >= d) incl += t;
  }
  if (lane == 63) wsum[wid] = incl;
  __syncthreads();
  int woff = blkOff[b];
  for (int w = 0; w < wid; ++w) woff += wsum[w];
  int run = woff + incl - s;
  int i0 = (b * 256 + tid) * 4;
  int r0 = run, r1 = r0 + v.x, r2 = r1 + v.y, r3 = r2 + v.z;
  start[i0 + 0] = r0; start[i0 + 1] = r1; start[i0 + 2] = r2; start[i0 + 3] = r3;
  cnt[i0 + 0] = r0; cnt[i0 + 1] = r1; cnt[i0 + 2] = r2; cnt[i0 + 3] = r3;  // cursor
}

// ---------------- pass 3: reorder + precompute 64B particle payload ----------------
// payload[pos] = { (px,py,pz,mvx), (mvy,mvz,a0,a1), (a2,a3,a4,a5), (a6,a7,a8,ORIG) }
__global__ __launch_bounds__(256) void k_reorder(
    const float* __restrict__ x, const float* __restrict__ v,
    const float* __restrict__ C, const float* __restrict__ S,
    int* __restrict__ cursor, float4* __restrict__ pay) {
  int n = blockIdx.x * 256 + threadIdx.x;
  if (n >= N_PART) return;

  float px = x[n * 3 + 0], py = x[n * 3 + 1], pz = x[n * 3 + 2];
  int bx = min(max((int)floorf(px * INV_DX - 0.5f), 0), N_GRID - 1);
  int by = min(max((int)floorf(py * INV_DX - 0.5f), 0), N_GRID - 1);
  int bz = min(max((int)floorf(pz * INV_DX - 0.5f), 0), N_GRID - 1);
  int c = (bx << 14) | (by << 7) | bz;
  int pos = atomicAdd(&cursor[c], 1);

  float mvx = P_MASS * v[n * 3 + 0];
  float mvy = P_MASS * v[n * 3 + 1];
  float mvz = P_MASS * v[n * 3 + 2];
  float aff[9];
#pragma unroll
  for (int k = 0; k < 9; ++k)
    aff[k] = AFF_COEF * S[n * 9 + k] + P_MASS * C[n * 9 + k];

  float4* dst = pay + (size_t)pos * 4;
  dst[0] = make_float4(px, py, pz, mvx);
  dst[1] = make_float4(mvy, mvz, aff[0], aff[1]);
  dst[2] = make_float4(aff[2], aff[3], aff[4], aff[5]);
  dst[3] = make_float4(aff[6], aff[7], aff[8], __int_as_float(n));  // orig idx in pad
}

// quadratic B-spline weight for static offset o (folds after unroll)
__device__ __forceinline__ float wq(int o, float f) {
  if (o == 0) return 0.5f * (1.5f - f) * (1.5f - f);
  if (o == 1) return 0.75f - (f - 1.0f) * (f - 1.0f);
  return 0.5f * (f - 0.5f) * (f - 0.5f);
}

// ---------------- P2G gather: dense bbox launch + bijective XCD swizzle ----------------
__global__ __launch_bounds__(256) void mpm_p2g(
    const int* __restrict__ start, const float4* __restrict__ pay,
    const int* __restrict__ bbox,
    float* __restrict__ grid /* [N_GRID3][4] final velocities */) {
  int bx0 = bbox[0], by0 = bbox[1], bz0c = bbox[2];
  int nxd = bbox[3] - bx0 + 3;   // nodes touched per axis = cells + 2
  int nyd = bbox[4] - by0 + 3;
  int nzd = bbox[5] - bz0c + 3;
  int dimzq = (nzd + ZQ - 1) / ZQ;
  int vol = nxd * nyd * dimzq;
  int nact = (vol + 255) >> 8;          // active blocks

  int bid = blockIdx.x;
  if (bid >= nact) return;
  // bijective XCD swizzle (m204): xcd = bid % 8 owns a contiguous wgid chunk
  int q = nact >> 3, r = nact & 7;
  int xcd = bid & 7, sub = bid >> 3;
  int wgid = (xcd < r ? xcd * (q + 1) : r * (q + 1) + (xcd - r) * q) + sub;

  int t = wgid * 256 + (int)threadIdx.x;
  if (t >= vol) return;
  int izq = t % dimzq;
  int rr = t / dimzq;
  int iy = rr % nyd;
  int ix = rr / nyd;
  int nx = bx0 + ix, ny = by0 + iy, nz0 = bz0c + izq * ZQ;
  if (nx > N_GRID - 1 || ny > N_GRID - 1) return;
  int zb0 = nz0 - 2;  // first contributing cell

  float accx[ZQ], accy[ZQ], accz[ZQ], accm[ZQ];
#pragma unroll
  for (int k = 0; k < ZQ; ++k) { accx[k] = 0.f; accy[k] = 0.f; accz[k] = 0.f; accm[k] = 0.f; }
  int gotmask = 0;

#pragma unroll
  for (int dy = -2; dy <= 0; ++dy) {
    int cy = ny + dy;
    if (cy < 0) continue;
#pragma unroll
    for (int dx = -2; dx <= 0; ++dx) {
      int cx = nx + dx;
      if (cx < 0) continue;
      const int ox = -dx, oy = -dy;  // static after unroll
      int rowb = (cx << 14) | (cy << 7);

      int S[ZQ + 3];
#pragma unroll
      for (int j = 0; j < ZQ + 3; ++j)
        S[j] = start[rowb + min(max(zb0 + j, 0), N_GRID)];
#pragma unroll
      for (int k = 0; k < ZQ; ++k)
        gotmask |= (S[k + 3] > S[k]) ? (1 << k) : 0;

      for (int i = S[0]; i < S[ZQ + 2]; ++i) {
        const float4* src = pay + (size_t)i * 4;
        float4 q0 = src[0], q1 = src[1], q2 = src[2], q3 = src[3];

        float fx = q0.x * INV_DX - (float)cx;   // base_x == cx by construction
        float fy = q0.y * INV_DX - (float)cy;
        float gz = q0.z * INV_DX;
        float bzf = floorf(gz - 0.5f);
        float fz = gz - bzf;
        int oz0 = nz0 - (int)bzf;

        float wxy = wq(ox, fx) * wq(oy, fy);
        float dpx = ((float)ox - fx) * DX;
        float dpy = ((float)oy - fy) * DX;
        float wz0 = 0.5f * (1.5f - fz) * (1.5f - fz);
        float wz1 = 0.75f - (fz - 1.0f) * (fz - 1.0f);
        float wz2 = 0.5f * (fz - 0.5f) * (fz - 0.5f);

        float sx = q0.w + q1.z * dpx + q1.w * dpy;
        float sy = q1.x + q2.y * dpx + q2.z * dpy;
        float sz = q1.y + q3.x * dpx + q3.y * dpy;
        float wm = wxy * P_MASS;

#pragma unroll
        for (int k = 0; k < ZQ; ++k) {
          int oz = oz0 + k;
          if (oz < 0 || oz > 2) continue;
          float wzz = (oz == 0) ? wz0 : ((oz == 1) ? wz1 : wz2);
          float w = wxy * wzz;
          float dpz = ((float)oz - fz) * DX;
          accx[k] += w * (sx + q2.x * dpz);
          accy[k] += w * (sy + q2.w * dpz);
          accz[k] += w * (sz + q3.z * dpz);
          accm[k] += wzz * wm;
        }
      }
    }
  }

  if (!gotmask) return;

  float4* g4 = (float4*)grid;
#pragma unroll
  for (int k = 0; k < ZQ; ++k) {
    int nz = nz0 + k;
    if (!((gotmask >> k) & 1) || nz > N_GRID - 1) continue;
    float m = accm[k];
    float ovx = 0.0f, ovy = 0.0f, ovz = 0.0f;
    if (m > 0.0f) {
      float inv = 1.0f / fmaxf(m, 1e-10f);
      ovx = accx[k] * inv;
      ovy = accy[k] * inv;
      ovz = accz[k] * inv;
      ovy -= DT * GRAVITY;
    }
    if (nx < BOUND && ovx < 0.0f) ovx = 0.0f;
    if (nx >= N_GRID - BOUND && ovx > 0.0f) ovx = 0.0f;
    if (ny < BOUND && ovy < 0.0f) ovy = 0.0f;
    if (ny >= N_GRID - BOUND && ovy > 0.0f) ovy = 0.0f;
    if (nz < BOUND && ovz < 0.0f) ovz = 0.0f;
    if (nz >= N_GRID - BOUND && ovz > 0.0f) ovz = 0.0f;
    g4[(nx << 14) | (ny << 7) | nz] = make_float4(ovx, ovy, ovz, m);
  }
}

// ---------------- G2P: SORTED order — spatially-coherent grid gather ----------------
// Thread i processes the i-th SORTED particle: adjacent lanes are z-neighbors so
// the 27 grid taps overlap ~2/3 between lanes (L1/L2-resident). Position comes
// from the payload; F read + output writes go through the original index.
__global__ __launch_bounds__(256) void mpm_g2p(
    const float4* __restrict__ pay, const float* __restrict__ F,
    const float* __restrict__ grid,
    float* __restrict__ out_x, float* __restrict__ out_v,
    float* __restrict__ out_C, float* __restrict__ out_F) {
  int i = blockIdx.x * blockDim.x + threadIdx.x;
  if (i >= N_PART) return;

  const float4* src = pay + (size_t)i * 4;
  float4 q0 = src[0];
  float4 q3 = src[3];
  int n = __float_as_int(q3.w);  // original particle index

  float px = q0.x, py = q0.y, pz = q0.z;
  float gx = px * INV_DX, gy = py * INV_DX, gz = pz * INV_DX;
  int bx = (int)floorf(gx - 0.5f);
  int by = (int)floorf(gy - 0.5f);
  int bz = (int)floorf(gz - 0.5f);
  float fx = gx - (float)bx, fy = gy - (float)by, fz = gz - (float)bz;

  float wx[3], wy[3], wz[3];
  wx[0] = 0.5f * (1.5f - fx) * (1.5f - fx);
  wx[1] = 0.75f - (fx - 1.0f) * (fx - 1.0f);
  wx[2] = 0.5f * (fx - 0.5f) * (fx - 0.5f);
  wy[0] = 0.5f * (1.5f - fy) * (1.5f - fy);
  wy[1] = 0.75f - (fy - 1.0f) * (fy - 1.0f);
  wy[2] = 0.5f * (fy - 0.5f) * (fy - 0.5f);
  wz[0] = 0.5f * (1.5f - fz) * (1.5f - fz);
  wz[1] = 0.75f - (fz - 1.0f) * (fz - 1.0f);
  wz[2] = 0.5f * (fz - 0.5f) * (fz - 0.5f);

  float vnx = 0.0f, vny = 0.0f, vnz = 0.0f;
  float Cn[9];
#pragma unroll
  for (int k = 0; k < 9; ++k) Cn[k] = 0.0f;

  const float4* g4 = (const float4*)grid;
#pragma unroll
  for (int a = 0; a < 3; ++a) {
#pragma unroll
    for (int bb = 0; bb < 3; ++bb) {
#pragma unroll
      for (int c = 0; c < 3; ++c) {
        float weight = wx[a] * wy[bb] * wz[c];
        float dpx = ((float)a - fx) * DX;
        float dpy = ((float)bb - fy) * DX;
        float dpz = ((float)c - fz) * DX;
        int nxg = min(max(bx + a, 0), N_GRID - 1);
        int nyg = min(max(by + bb, 0), N_GRID - 1);
        int nzg = min(max(bz + c, 0), N_GRID - 1);
        int flat = (nxg * N_GRID + nyg) * N_GRID + nzg;
        float4 g = g4[flat];
        vnx += weight * g.x;
        vny += weight * g.y;
        vnz += weight * g.z;
        Cn[0] += weight * g.x * dpx;
        Cn[1] += weight * g.x * dpy;
        Cn[2] += weight * g.x * dpz;
        Cn[3] += weight * g.y * dpx;
        Cn[4] += weight * g.y * dpy;
        Cn[5] += weight * g.y * dpz;
        Cn[6] += weight * g.z * dpx;
        Cn[7] += weight * g.z * dpy;
        Cn[8] += weight * g.z * dpz;
      }
    }
  }

#pragma unroll
  for (int k = 0; k < 9; ++k) Cn[k] *= C_SCALE;

  out_x[n * 3 + 0] = px + DT * vnx;
  out_x[n * 3 + 1] = py + DT * vny;
  out_x[n * 3 + 2] = pz + DT * vnz;
  out_v[n * 3 + 0] = vnx;
  out_v[n * 3 + 1] = vny;
  out_v[n * 3 + 2] = vnz;

  float A[9];
#pragma unroll
  for (int k = 0; k < 9; ++k) A[k] = DT * Cn[k];
  A[0] += 1.0f; A[4] += 1.0f; A[8] += 1.0f;

  float Fl[9];
#pragma unroll
  for (int k = 0; k < 9; ++k) Fl[k] = F[n * 9 + k];

#pragma unroll
  for (int r = 0; r < 3; ++r) {
#pragma unroll
    for (int k = 0; k < 3; ++k) {
      float s = A[r * 3 + 0] * Fl[0 * 3 + k] +
                A[r * 3 + 1] * Fl[1 * 3 + k] +
                A[r * 3 + 2] * Fl[2 * 3 + k];
      out_F[n * 9 + r * 3 + k] = s;
    }
  }

#pragma unroll
  for (int k = 0; k < 9; ++k) out_C[n * 9 + k] = Cn[k];
}

extern "C" void kernel_launch(void* const* d_in, const int* in_sizes, int n_in,
                              void* d_out, int out_size, void* d_ws, size_t ws_size,
                              hipStream_t stream) {
  const float* x      = (const float*)d_in[0];
  const float* v      = (const float*)d_in[1];
  const float* C      = (const float*)d_in[2];
  const float* F      = (const float*)d_in[3];
  const float* stress = (const float*)d_in[4];

  float* out = (float*)d_out;
  char*  ws  = (char*)d_ws;

  const size_t GRID_BYTES  = (size_t)N_GRID3 * 4 * sizeof(float);   // 33.5 MB
  const size_t PAY_BYTES   = (size_t)N_PART * 4 * sizeof(float4);   // 32 MB
  const size_t CNT_BYTES   = (size_t)N_GRID3 * sizeof(int);         // 8 MB
  const size_t START_BYTES = ((size_t)N_GRID3 + 1) * sizeof(int);   // 8 MB

  int pblocks = (N_PART + 255) / 256;  // 1954

  float*  grid   = (float*)ws;
  float4* pay    = (float4*)(ws + GRID_BYTES);
  int*    cnt    = (int*)(ws + GRID_BYTES + PAY_BYTES);             // doubles as cursor
  int*    startp = (int*)(ws + GRID_BYTES + PAY_BYTES + CNT_BYTES);
  int*    blkSum = (int*)(ws + GRID_BYTES + PAY_BYTES + CNT_BYTES + START_BYTES);
  int*    blkOff = blkSum + 2048;
  int*    blkMin = blkOff + 2048;      // pblocks * 3
  int*    blkMax = blkMin + pblocks * 3;
  int*    bbox   = blkMax + pblocks * 3;  // 6 ints

  hipMemsetAsync(cnt, 0, CNT_BYTES, stream);

  k_count<<<pblocks, 256, 0, stream>>>(x, cnt, blkMin, blkMax);
  k_scan1<<<2048, 256, 0, stream>>>(cnt, blkSum);
  k_scan2<<<1, 256, 0, stream>>>(blkSum, blkOff, startp, blkMin, blkMax, pblocks, bbox);
  k_scan3<<<2048, 256, 0, stream>>>(cnt, blkOff, startp);
  k_reorder<<<pblocks, 256, 0, stream>>>(x, v, C, stress, cnt, pay);

  // worst-case grid covers the full domain; swizzle + exits handled in-kernel
  mpm_p2g<<<(N_GRID3 / ZQ + 255) / 256, 256, 0, stream>>>(startp, pay, bbox, grid);

  float* out_x = out;
  float* out_v = out + (size_t)N_PART * 3;
  float* out_C = out + (size_t)N_PART * 6;
  float* out_F = out + (size_t)N_PART * 6 + (size_t)N_PART * 9;
  mpm_g2p<<<pblocks, 256, 0, stream>>>(pay, F, grid, out_x, out_v, out_C, out_F);
}